// Round 11
// baseline (396.369 us; speedup 1.0000x reference)
//
#include <hip/hip_runtime.h>
#include <math.h>
#include <stdint.h>

// Problem constants: BS=16, SEQ=1024, NV=512, DM=256, K=8
#define BS 16
#define SEQ 1024
#define NV 512
#define DM 256
#define NK 8

typedef __attribute__((ext_vector_type(8))) short bf16x8;
typedef __attribute__((ext_vector_type(4))) float f32x4;

// ---------------------------------------------------------------------------
// Module-global scratch. Every launch fully overwrites before reading.
// bf16 3-way splits: x transposed to [b][v][s] (s-major = A-fragment order),
// W kept [d][s] (s-major = B-fragment order). g_zp is GONE: with MFMA the
// only consumer of z is nn2, computed in-block (full-K tiles).
// ---------------------------------------------------------------------------
__device__ double g_WC[NK * SEQ];                               // 64 KB
__device__ double g_Bk[NK];                                     // 64 B
__device__ __align__(16) unsigned short g_x0[BS * NV * SEQ];    // 16 MB
__device__ __align__(16) unsigned short g_x1[BS * NV * SEQ];    // 16 MB
__device__ __align__(16) unsigned short g_x2[BS * NV * SEQ];    // 16 MB
__device__ __align__(16) unsigned short g_w0[DM * SEQ];         // 512 KB
__device__ __align__(16) unsigned short g_w1[DM * SEQ];         // 512 KB
__device__ __align__(16) unsigned short g_w2[DM * SEQ];         // 512 KB
__device__ double g_nn2p[2][BS * NV];                           // 128 KB
__device__ double g_Dp[8 * BS * NV * NK];                       // 4 MB
__device__ unsigned char g_bits[BS * NV];                       // 8 KB

// ---------------------------------------------------------------------------
// Exact JAX threefry2x32 (20 rounds), key = PRNGKey(7) = (0, 7).
// ---------------------------------------------------------------------------
__device__ __forceinline__ void threefry2x32_key7(uint32_t x0, uint32_t x1,
                                                  uint32_t& o0, uint32_t& o1) {
    const uint32_t k0 = 0u, k1 = 7u;
    const uint32_t k2 = k0 ^ k1 ^ 0x1BD11BDAu;
    uint32_t v0 = x0 + k0, v1 = x1 + k1;
#define TF_ROUND(r) { v0 += v1; v1 = (v1 << (r)) | (v1 >> (32 - (r))); v1 ^= v0; }
    TF_ROUND(13) TF_ROUND(15) TF_ROUND(26) TF_ROUND(6)
    v0 += k1; v1 += k2 + 1u;
    TF_ROUND(17) TF_ROUND(29) TF_ROUND(16) TF_ROUND(24)
    v0 += k2; v1 += k0 + 2u;
    TF_ROUND(13) TF_ROUND(15) TF_ROUND(26) TF_ROUND(6)
    v0 += k0; v1 += k1 + 3u;
    TF_ROUND(17) TF_ROUND(29) TF_ROUND(16) TF_ROUND(24)
    v0 += k1; v1 += k2 + 4u;
    TF_ROUND(13) TF_ROUND(15) TF_ROUND(26) TF_ROUND(6)
    v0 += k2; v1 += k0 + 5u;
#undef TF_ROUND
    o0 = v0; o1 = v1;
}

__device__ __forceinline__ float bits_to_uniform(uint32_t b) {
    return __uint_as_float((b >> 9) | 0x3F800000u) - 1.0f;
}

// bf16 split helpers (RNE; residuals exact by Sterbenz).
__device__ __forceinline__ unsigned short f2bf(float f) {
    uint32_t u = __float_as_uint(f);
    return (unsigned short)((u + 0x7FFFu + ((u >> 16) & 1u)) >> 16);
}
__device__ __forceinline__ float bf2f(unsigned short h) {
    return __uint_as_float(((uint32_t)h) << 16);
}
__device__ __forceinline__ void split3(float f, unsigned short& h0,
                                       unsigned short& h1, unsigned short& h2) {
    h0 = f2bf(f);
    float r1 = f - bf2f(h0);
    h1 = f2bf(r1);
    float r2 = r1 - bf2f(h1);
    h2 = f2bf(r2);
}

// Async global->LDS 16B copy: LDS dest = wave-uniform base + lane*16,
// global source PER-LANE.
__device__ __forceinline__ void cp16s(const unsigned short* g, unsigned short* l) {
    __builtin_amdgcn_global_load_lds(
        (const __attribute__((address_space(1))) void*)g,
        (__attribute__((address_space(3))) void*)l,
        16, 0, 0);
}

// ---------------------------------------------------------------------------
// Prep (r10 verbatim): blocks 0..31 = WC/Bk fp64; 32..95 = W 3-way split.
// ---------------------------------------------------------------------------
__global__ __launch_bounds__(256) void prep_kernel(
        const float* __restrict__ W, const float* __restrict__ bias,
        const float* __restrict__ ce) {
    __shared__ double red[256];
    __shared__ double cen[256];
    const int t = threadIdx.x;
    const int bid = blockIdx.x;

    if (bid >= 32) {
        const int base = (bid - 32) * 4096 + t * 16;
        uint32_t p0[8], p1[8], p2[8];
#pragma unroll
        for (int i = 0; i < 16; ++i) {
            unsigned short h0, h1, h2;
            split3(W[base + i], h0, h1, h2);
            if (i & 1) {
                p0[i >> 1] |= (uint32_t)h0 << 16;
                p1[i >> 1] |= (uint32_t)h1 << 16;
                p2[i >> 1] |= (uint32_t)h2 << 16;
            } else {
                p0[i >> 1] = h0; p1[i >> 1] = h1; p2[i >> 1] = h2;
            }
        }
        *(uint4*)&g_w0[base]     = make_uint4(p0[0], p0[1], p0[2], p0[3]);
        *(uint4*)&g_w0[base + 8] = make_uint4(p0[4], p0[5], p0[6], p0[7]);
        *(uint4*)&g_w1[base]     = make_uint4(p1[0], p1[1], p1[2], p1[3]);
        *(uint4*)&g_w1[base + 8] = make_uint4(p1[4], p1[5], p1[6], p1[7]);
        *(uint4*)&g_w2[base]     = make_uint4(p2[0], p2[1], p2[2], p2[3]);
        *(uint4*)&g_w2[base + 8] = make_uint4(p2[4], p2[5], p2[6], p2[7]);
        return;
    }

    const int k = bid >> 2;
    const int schunk = bid & 3;

    double c = (double)ce[k * DM + t];
    red[t] = c * c;
    __syncthreads();
    for (int off = 128; off > 0; off >>= 1) {
        if (t < off) red[t] += red[t + off];
        __syncthreads();
    }
    double nc = fmax(sqrt(red[0]), 1e-12);
    cen[t] = c / nc;
    __syncthreads();
    red[t] = (double)bias[t] * cen[t];
    __syncthreads();
    for (int off = 128; off > 0; off >>= 1) {
        if (t < off) red[t] += red[t + off];
        __syncthreads();
    }
    if (t == 0 && schunk == 0) g_Bk[k] = red[0];

    const int s = schunk * 256 + t;
    double acc = 0.0;
#pragma unroll 8
    for (int d = 0; d < DM; ++d)
        acc += cen[d] * (double)W[(size_t)d * SEQ + s];
    g_WC[(size_t)k * SEQ + s] = acc;
}

// ---------------------------------------------------------------------------
// x transpose + 3-way bf16 split (r10 verbatim). Grid (128, 16).
// ---------------------------------------------------------------------------
__global__ __launch_bounds__(256) void xsplit_kernel(const float* __restrict__ x) {
    __shared__ float tile[64][65];
    const int t = threadIdx.x;
    const int stile = blockIdx.x >> 3, vtile = blockIdx.x & 7;
    const int b = blockIdx.y;
    const int s0 = stile * 64, v0 = vtile * 64;
    const float* xb = x + ((size_t)b * SEQ + s0) * NV + v0;

#pragma unroll
    for (int p = 0; p < 16; ++p) {
        int lin = p * 256 + t;
        int sl = lin >> 6, vv = lin & 63;
        tile[sl][vv] = xb[(size_t)sl * NV + vv];
    }
    __syncthreads();

    const int vr = t >> 2, g = t & 3;
    const size_t obase = ((size_t)b * NV + v0 + vr) * SEQ + s0 + g * 16;
    uint32_t p0[8], p1[8], p2[8];
#pragma unroll
    for (int i = 0; i < 16; ++i) {
        unsigned short h0, h1, h2;
        split3(tile[g * 16 + i][vr], h0, h1, h2);
        if (i & 1) {
            p0[i >> 1] |= (uint32_t)h0 << 16;
            p1[i >> 1] |= (uint32_t)h1 << 16;
            p2[i >> 1] |= (uint32_t)h2 << 16;
        } else {
            p0[i >> 1] = h0; p1[i >> 1] = h1; p2[i >> 1] = h2;
        }
    }
    *(uint4*)&g_x0[obase]     = make_uint4(p0[0], p0[1], p0[2], p0[3]);
    *(uint4*)&g_x0[obase + 8] = make_uint4(p0[4], p0[5], p0[6], p0[7]);
    *(uint4*)&g_x1[obase]     = make_uint4(p1[0], p1[1], p1[2], p1[3]);
    *(uint4*)&g_x1[obase + 8] = make_uint4(p1[4], p1[5], p1[6], p1[7]);
    *(uint4*)&g_x2[obase]     = make_uint4(p2[0], p2[1], p2[2], p2[3]);
    *(uint4*)&g_x2[obase + 8] = make_uint4(p2[4], p2[5], p2[6], p2[7]);
}

// ---------------------------------------------------------------------------
// GEMM v11: full-K MFMA + fused nn2 (g_zp eliminated).
// Tile 32v x 128d x 1024s; grid (dblk2, v16, b16) = 512 blocks = 2/CU
// (8 waves/CU). Wave w owns d [32w, 32w+32) = 2 n-tiles; 2 m-tiles of v.
// LDS double-buffered (2 x 30 KB + 1 KB reduce = 61 KB), ONE barrier/chunk:
//   STAGE(c+1 -> buf^1) async; ds_read+24 MFMA on buf; __syncthreads().
// Numerics: fp32 MFMA acc per 256-s quarter, flushed to fp64 zacc in order
// ((q0+q1)+q2)+q3 -- bit-identical partial structure to r10 (absmax 0).
// Epilogue: z = zacc + bias (fp64), nn2 = sum_d z^2 via shfl-reduce over the
// 16-lane col groups + LDS reduce over waves -> g_nn2p[dblk] (64 KB).
// XOR k-group swizzle on LDS (r10-proven): staged slot S of row R holds
// k-group S^(R&3); fragment read slot (l>>4)^(l&3).
// ---------------------------------------------------------------------------
#define KC 32

__global__ __launch_bounds__(256) void gemm_kernel(const float* __restrict__ bias) {
    __shared__ __align__(16) unsigned short xs[2][3][32 * 32];    // 12 KB
    __shared__ __align__(16) unsigned short ws[2][3][128 * 32];   // 48 KB
    __shared__ double dred[4][32];                                // 1 KB

    const int t = threadIdx.x;
    const int dblk = blockIdx.x;    // 0..1
    const int vt   = blockIdx.y;    // 0..15
    const int b    = blockIdx.z;    // 0..15
    const int v0 = vt * 32, d0 = dblk * 128;
    const int w = t >> 6, l = t & 63;

    // Staging: lane l fills row base+(l>>2), slot l&3 = k-group (l&3)^(row&3).
    const int srow = l >> 2;
    const int sk8  = ((l & 3) ^ ((l >> 2) & 3)) * 8;
    // Fragment read: row l&15, k-group l>>4 at slot (l>>4)^(l&3).
    const int rrow = l & 15;
    const int rsl  = ((l >> 4) ^ (l & 3)) * 8;

    const size_t xbase = ((size_t)b * NV + v0) * SEQ;
    const size_t wbase = (size_t)d0 * SEQ;
    const unsigned short* xsrc[3] = {g_x0 + xbase, g_x1 + xbase, g_x2 + xbase};
    const unsigned short* wsrc[3] = {g_w0 + wbase, g_w1 + wbase, g_w2 + wbase};

    f32x4 acc[2][2];
    double zac[2][2][4];
#pragma unroll
    for (int mb = 0; mb < 2; ++mb)
#pragma unroll
        for (int nb = 0; nb < 2; ++nb) {
            acc[mb][nb] = (f32x4){0.f, 0.f, 0.f, 0.f};
#pragma unroll
            for (int r = 0; r < 4; ++r) zac[mb][nb][r] = 0.0;
        }

    // Per chunk: wave w stages its 32 W rows x 3 splits (6 cp16); waves 0-2
    // stage x split w (2 cp16 each). Wave-uniform branch.
#define STAGE(BUF, C)                                                          \
    {                                                                          \
        const int S0 = (C) * KC;                                               \
        _Pragma("unroll")                                                      \
        for (int sp = 0; sp < 3; ++sp) {                                       \
            cp16s(&wsrc[sp][(size_t)(w * 32 + srow) * SEQ + S0 + sk8],         \
                  &ws[BUF][sp][(w * 32) * 32]);                                \
            cp16s(&wsrc[sp][(size_t)(w * 32 + 16 + srow) * SEQ + S0 + sk8],    \
                  &ws[BUF][sp][(w * 32 + 16) * 32]);                           \
        }                                                                      \
        if (w < 3) {                                                           \
            cp16s(&xsrc[w][(size_t)srow * SEQ + S0 + sk8], &xs[BUF][w][0]);    \
            cp16s(&xsrc[w][(size_t)(16 + srow) * SEQ + S0 + sk8],              \
                  &xs[BUF][w][16 * 32]);                                       \
        }                                                                      \
    }

    STAGE(0, 0)
    __syncthreads();

    for (int c = 0; c < 32; ++c) {
        const int buf = c & 1;
        if (c < 31) STAGE(buf ^ 1, c + 1)   // async into other buffer

        bf16x8 a[3][2], bb[3][2];
#pragma unroll
        for (int sp = 0; sp < 3; ++sp) {
#pragma unroll
            for (int mb = 0; mb < 2; ++mb)
                a[sp][mb] = *(const bf16x8*)&xs[buf][sp][(mb * 16 + rrow) * 32 + rsl];
#pragma unroll
            for (int nb = 0; nb < 2; ++nb)
                bb[sp][nb] = *(const bf16x8*)
                    &ws[buf][sp][(w * 32 + nb * 16 + rrow) * 32 + rsl];
        }
#pragma unroll
        for (int mb = 0; mb < 2; ++mb)
#pragma unroll
            for (int nb = 0; nb < 2; ++nb) {
                f32x4 v = acc[mb][nb];
                v = __builtin_amdgcn_mfma_f32_16x16x32_bf16(a[1][mb], bb[1][nb], v, 0, 0, 0);
                v = __builtin_amdgcn_mfma_f32_16x16x32_bf16(a[0][mb], bb[2][nb], v, 0, 0, 0);
                v = __builtin_amdgcn_mfma_f32_16x16x32_bf16(a[2][mb], bb[0][nb], v, 0, 0, 0);
                v = __builtin_amdgcn_mfma_f32_16x16x32_bf16(a[0][mb], bb[1][nb], v, 0, 0, 0);
                v = __builtin_amdgcn_mfma_f32_16x16x32_bf16(a[1][mb], bb[0][nb], v, 0, 0, 0);
                v = __builtin_amdgcn_mfma_f32_16x16x32_bf16(a[0][mb], bb[0][nb], v, 0, 0, 0);
                acc[mb][nb] = v;
            }

        if ((c & 7) == 7) {   // quarter boundary: flush fp32 partial to fp64
#pragma unroll
            for (int mb = 0; mb < 2; ++mb)
#pragma unroll
                for (int nb = 0; nb < 2; ++nb) {
#pragma unroll
                    for (int r = 0; r < 4; ++r)
                        zac[mb][nb][r] += (double)acc[mb][nb][r];
                    acc[mb][nb] = (f32x4){0.f, 0.f, 0.f, 0.f};
                }
        }

        __syncthreads();   // drains DMA; protects buf for next restage
    }
#undef STAGE

    // Epilogue: z = zac + bias (fp64); nn2 partial over this block's 128 d.
    double sv[2][4];
#pragma unroll
    for (int mb = 0; mb < 2; ++mb)
#pragma unroll
        for (int r = 0; r < 4; ++r) sv[mb][r] = 0.0;
#pragma unroll
    for (int mb = 0; mb < 2; ++mb)
#pragma unroll
        for (int nb = 0; nb < 2; ++nb) {
            const int d = d0 + w * 32 + nb * 16 + (l & 15);
            const double bd = (double)bias[d];
#pragma unroll
            for (int r = 0; r < 4; ++r) {
                double z = zac[mb][nb][r] + bd;
                sv[mb][r] += z * z;
            }
        }
    // Reduce over the 16 cols (lanes l&15) of each row group.
#pragma unroll
    for (int mb = 0; mb < 2; ++mb)
#pragma unroll
        for (int r = 0; r < 4; ++r) {
            double s = sv[mb][r];
            s += __shfl_xor(s, 1);
            s += __shfl_xor(s, 2);
            s += __shfl_xor(s, 4);
            s += __shfl_xor(s, 8);
            sv[mb][r] = s;
        }
    if ((l & 15) == 0) {
#pragma unroll
        for (int mb = 0; mb < 2; ++mb)
#pragma unroll
            for (int r = 0; r < 4; ++r)
                dred[w][mb * 16 + (l >> 4) * 4 + r] = sv[mb][r];
    }
    __syncthreads();
    if (t < 32) {
        double s = dred[0][t] + dred[1][t] + dred[2][t] + dred[3][t];
        g_nn2p[dblk][b * NV + v0 + t] = s;
    }
}

// ---------------------------------------------------------------------------
// D-kernel (proven baseline): D_k partials over 128-s chunks, fp64.
// Grid: (vblk=8, b=16, sc=8) = 1024 blocks.
// ---------------------------------------------------------------------------
__global__ __launch_bounds__(256) void dkern(const float* __restrict__ x) {
    __shared__ double wcd[NK][128];
    __shared__ double dw[4][64][NK];
    const int t = threadIdx.x;
    const int vblk = blockIdx.x;
    const int b    = blockIdx.y;
    const int sc   = blockIdx.z;
    const int v0 = vblk * 64;
    const int ss = sc * 128;

#pragma unroll
    for (int j = 0; j < 4; ++j) {
        int idx = j * 256 + t;
        ((double*)wcd)[idx] = g_WC[(size_t)(idx >> 7) * SEQ + ss + (idx & 127)];
    }
    __syncthreads();

    const int vl = t & 63, w = t >> 6;
    const float* xp = x + (size_t)b * SEQ * NV + v0 + vl;
    double D[NK];
#pragma unroll
    for (int k = 0; k < NK; ++k) D[k] = 0.0;
    const int sw = w * 32;
    for (int i = 0; i < 32; ++i) {
        int sl = sw + i;
        double xv = (double)xp[(size_t)(ss + sl) * NV];
#pragma unroll
        for (int k = 0; k < NK; ++k) D[k] += xv * wcd[k][sl];
    }
#pragma unroll
    for (int k = 0; k < NK; ++k) dw[w][vl][k] = D[k];
    __syncthreads();

    const int v = t & 63, k2 = (t >> 6) * 2;
#pragma unroll
    for (int j = 0; j < 2; ++j) {
        int k = k2 + j;
        double s = dw[0][v][k] + dw[1][v][k] + dw[2][v][k] + dw[3][v][k];
        g_Dp[(((size_t)sc * BS + b) * NV + v0 + v) * NK + k] = s;
    }
}

// ---------------------------------------------------------------------------
// Finalize: n from the two deterministic dblk nn2 partials; rest unchanged.
// ---------------------------------------------------------------------------
__global__ __launch_bounds__(256) void finalize_kernel() {
    const int bv = blockIdx.x * 256 + threadIdx.x;
    double n = fmax(sqrt(g_nn2p[0][bv] + g_nn2p[1][bv]), 1e-12);

    double D[NK];
#pragma unroll
    for (int k = 0; k < NK; ++k) D[k] = g_Bk[k];
#pragma unroll
    for (int sc = 0; sc < 8; ++sc) {
#pragma unroll
        for (int k = 0; k < NK; ++k)
            D[k] += g_Dp[((size_t)sc * (BS * NV) + bv) * NK + k];
    }

    double p[NK], sum = 0.0;
#pragma unroll
    for (int k = 0; k < NK; ++k) {
        p[k] = exp((D[k] / n) / 0.05);
        sum += p[k];
    }
    unsigned int byte = 0;
#pragma unroll
    for (int k = 0; k < NK; ++k) {
        uint32_t i = (uint32_t)(k * (BS * NV) + bv);
        uint32_t y0, y1;
        threefry2x32_key7(0u, i, y0, y1);
        float u = bits_to_uniform(y0 ^ y1);
        if ((double)u < p[k] / sum) byte |= 1u << k;
    }
    g_bits[bv] = (unsigned char)byte;
}

// ---------------------------------------------------------------------------
// Write (unchanged): 268 MB broadcast, float4 stores — at HBM floor.
// ---------------------------------------------------------------------------
__global__ __launch_bounds__(256) void write_kernel(float* __restrict__ out) {
    const int t = threadIdx.x;
    const size_t r0 = (size_t)blockIdx.x * 8;
#pragma unroll
    for (int j = 0; j < 8; ++j) {
        size_t r = r0 + j;
        unsigned int bv = (unsigned int)(r & 8191u);
        unsigned int k  = (unsigned int)(r >> 13);
        float v = ((g_bits[bv] >> k) & 1u) ? 1.0f : 0.0f;
        float4 val = make_float4(v, v, v, v);
        ((float4*)(out + r * 1024))[t] = val;
    }
}

// ---------------------------------------------------------------------------
extern "C" void kernel_launch(void* const* d_in, const int* in_sizes, int n_in,
                              void* d_out, int out_size, void* d_ws, size_t ws_size,
                              hipStream_t stream) {
    const float* x    = (const float*)d_in[0];
    const float* W    = (const float*)d_in[1];
    const float* bias = (const float*)d_in[2];
    const float* ce   = (const float*)d_in[3];
    float* out = (float*)d_out;

    prep_kernel<<<dim3(96), dim3(256), 0, stream>>>(W, bias, ce);
    xsplit_kernel<<<dim3(128, 16), dim3(256), 0, stream>>>(x);
    gemm_kernel<<<dim3(2, 16, 16), dim3(256), 0, stream>>>(bias);
    dkern<<<dim3(8, 16, 8), dim3(256), 0, stream>>>(x);
    finalize_kernel<<<dim3(32), dim3(256), 0, stream>>>();
    write_kernel<<<dim3(8192), dim3(256), 0, stream>>>(out);
}

// Round 12
// 368.464 us; speedup vs baseline: 1.0757x; 1.0757x over previous
//
#include <hip/hip_runtime.h>
#include <math.h>
#include <stdint.h>

// Problem constants: BS=16, SEQ=1024, NV=512, DM=256, K=8
#define BS 16
#define SEQ 1024
#define NV 512
#define DM 256
#define NK 8

typedef __attribute__((ext_vector_type(8))) short bf16x8;
typedef __attribute__((ext_vector_type(4))) float f32x4;

// ---------------------------------------------------------------------------
// Module-global scratch. Every launch fully overwrites before reading.
// x/W bf16 3-way splits stored in MFMA FRAGMENT ORDER:
//   x tile (b, vt=v>>4, kc=s>>5): elem (row=v&15, kslot=(s>>3)&3, e=s&7) at
//     ((((b*32+vt)*32+kc)*64 + (row|kslot<<4))*8 + e
//   W tile (dt=d>>4, kc): same lane mapping.
// -> gemm reads each lane's 16B fragment as a coalesced global load:
//    NO LDS, NO barriers in the gemm (kills the 8-way bank conflict and the
//    2-barrier drain); xsplit writes become contiguous 256B bursts.
// ---------------------------------------------------------------------------
__device__ double g_WC[NK * SEQ];                               // 64 KB
__device__ double g_Bk[NK];                                     // 64 B
__device__ __align__(16) unsigned short g_x0[BS * NV * SEQ];    // 16 MB
__device__ __align__(16) unsigned short g_x1[BS * NV * SEQ];    // 16 MB
__device__ __align__(16) unsigned short g_x2[BS * NV * SEQ];    // 16 MB
__device__ __align__(16) unsigned short g_w0[DM * SEQ];         // 512 KB
__device__ __align__(16) unsigned short g_w1[DM * SEQ];         // 512 KB
__device__ __align__(16) unsigned short g_w2[DM * SEQ];         // 512 KB
__device__ double g_nn2p[2][BS * NV];                           // 128 KB
__device__ double g_Dp[8 * BS * NV * NK];                       // 4 MB
__device__ unsigned char g_bits[BS * NV];                       // 8 KB

// ---------------------------------------------------------------------------
// Exact JAX threefry2x32 (20 rounds), key = PRNGKey(7) = (0, 7).
// ---------------------------------------------------------------------------
__device__ __forceinline__ void threefry2x32_key7(uint32_t x0, uint32_t x1,
                                                  uint32_t& o0, uint32_t& o1) {
    const uint32_t k0 = 0u, k1 = 7u;
    const uint32_t k2 = k0 ^ k1 ^ 0x1BD11BDAu;
    uint32_t v0 = x0 + k0, v1 = x1 + k1;
#define TF_ROUND(r) { v0 += v1; v1 = (v1 << (r)) | (v1 >> (32 - (r))); v1 ^= v0; }
    TF_ROUND(13) TF_ROUND(15) TF_ROUND(26) TF_ROUND(6)
    v0 += k1; v1 += k2 + 1u;
    TF_ROUND(17) TF_ROUND(29) TF_ROUND(16) TF_ROUND(24)
    v0 += k2; v1 += k0 + 2u;
    TF_ROUND(13) TF_ROUND(15) TF_ROUND(26) TF_ROUND(6)
    v0 += k0; v1 += k1 + 3u;
    TF_ROUND(17) TF_ROUND(29) TF_ROUND(16) TF_ROUND(24)
    v0 += k1; v1 += k2 + 4u;
    TF_ROUND(13) TF_ROUND(15) TF_ROUND(26) TF_ROUND(6)
    v0 += k2; v1 += k0 + 5u;
#undef TF_ROUND
    o0 = v0; o1 = v1;
}

__device__ __forceinline__ float bits_to_uniform(uint32_t b) {
    return __uint_as_float((b >> 9) | 0x3F800000u) - 1.0f;
}

// bf16 split helpers (RNE; residuals exact by Sterbenz).
__device__ __forceinline__ unsigned short f2bf(float f) {
    uint32_t u = __float_as_uint(f);
    return (unsigned short)((u + 0x7FFFu + ((u >> 16) & 1u)) >> 16);
}
__device__ __forceinline__ float bf2f(unsigned short h) {
    return __uint_as_float(((uint32_t)h) << 16);
}
__device__ __forceinline__ void split3(float f, unsigned short& h0,
                                       unsigned short& h1, unsigned short& h2) {
    h0 = f2bf(f);
    float r1 = f - bf2f(h0);
    h1 = f2bf(r1);
    float r2 = r1 - bf2f(h1);
    h2 = f2bf(r2);
}

// ---------------------------------------------------------------------------
// Prep: blocks 0..31 = WC/Bk fp64 (proven verbatim); blocks 32..95 =
// W 3-way split into fragment-order g_w{0,1,2}.
// ---------------------------------------------------------------------------
__global__ __launch_bounds__(256) void prep_kernel(
        const float* __restrict__ W, const float* __restrict__ bias,
        const float* __restrict__ ce) {
    __shared__ double red[256];
    __shared__ double cen[256];
    const int t = threadIdx.x;
    const int bid = blockIdx.x;

    if (bid >= 32) {
        const int base = (bid - 32) * 4096 + t * 16;   // 16 consecutive s
        const int d = base >> 10, s = base & 1023;
        const int dt = d >> 4, row = d & 15;
        const int kc = s >> 5, kslot = (s >> 3) & 3;   // kslot in {0,2}
        const size_t off0 = ((((size_t)dt * 32 + kc) * 64) + (row | (kslot << 4))) * 8;
        uint32_t p0[8], p1[8], p2[8];
#pragma unroll
        for (int i = 0; i < 16; ++i) {
            unsigned short h0, h1, h2;
            split3(W[base + i], h0, h1, h2);
            if (i & 1) {
                p0[i >> 1] |= (uint32_t)h0 << 16;
                p1[i >> 1] |= (uint32_t)h1 << 16;
                p2[i >> 1] |= (uint32_t)h2 << 16;
            } else {
                p0[i >> 1] = h0; p1[i >> 1] = h1; p2[i >> 1] = h2;
            }
        }
        // i 0..7 -> lane row|kslot<<4 ; i 8..15 -> lane row|(kslot+1)<<4 (+128)
        *(uint4*)&g_w0[off0]       = make_uint4(p0[0], p0[1], p0[2], p0[3]);
        *(uint4*)&g_w0[off0 + 128] = make_uint4(p0[4], p0[5], p0[6], p0[7]);
        *(uint4*)&g_w1[off0]       = make_uint4(p1[0], p1[1], p1[2], p1[3]);
        *(uint4*)&g_w1[off0 + 128] = make_uint4(p1[4], p1[5], p1[6], p1[7]);
        *(uint4*)&g_w2[off0]       = make_uint4(p2[0], p2[1], p2[2], p2[3]);
        *(uint4*)&g_w2[off0 + 128] = make_uint4(p2[4], p2[5], p2[6], p2[7]);
        return;
    }

    const int k = bid >> 2;
    const int schunk = bid & 3;

    double c = (double)ce[k * DM + t];
    red[t] = c * c;
    __syncthreads();
    for (int off = 128; off > 0; off >>= 1) {
        if (t < off) red[t] += red[t + off];
        __syncthreads();
    }
    double nc = fmax(sqrt(red[0]), 1e-12);
    cen[t] = c / nc;
    __syncthreads();
    red[t] = (double)bias[t] * cen[t];
    __syncthreads();
    for (int off = 128; off > 0; off >>= 1) {
        if (t < off) red[t] += red[t + off];
        __syncthreads();
    }
    if (t == 0 && schunk == 0) g_Bk[k] = red[0];

    const int s = schunk * 256 + t;
    double acc = 0.0;
#pragma unroll 8
    for (int d = 0; d < DM; ++d)
        acc += cen[d] * (double)W[(size_t)d * SEQ + s];
    g_WC[(size_t)k * SEQ + s] = acc;
}

// ---------------------------------------------------------------------------
// x transpose + 3-way split into fragment-order g_x{0,1,2}.
// Block = 64s x 64v tile (LDS transpose). Thread map: vr = t&63 (row of the
// v-dim), g = t>>6 (which 16-s group) -> writes from 64 consecutive threads
// land in contiguous 16B-lane order (256B bursts). Grid (128, 16).
// ---------------------------------------------------------------------------
__global__ __launch_bounds__(256) void xsplit_kernel(const float* __restrict__ x) {
    __shared__ float tile[64][65];
    const int t = threadIdx.x;
    const int stile = blockIdx.x >> 3, vtile = blockIdx.x & 7;
    const int b = blockIdx.y;
    const int s0 = stile * 64, v0 = vtile * 64;
    const float* xb = x + ((size_t)b * SEQ + s0) * NV + v0;

#pragma unroll
    for (int p = 0; p < 16; ++p) {
        int lin = p * 256 + t;
        int sl = lin >> 6, vv = lin & 63;
        tile[sl][vv] = xb[(size_t)sl * NV + vv];
    }
    __syncthreads();

    const int vr = t & 63, g = t >> 6;
    const int v = v0 + vr;
    const int s8 = s0 + g * 16;                    // first 8-elem group
    const int vt = v >> 4, row = v & 15;
    const int kc = s8 >> 5, kslot = (s8 >> 3) & 3; // in {0,2}
    const size_t off0 =
        ((((size_t)b * 32 + vt) * 32 + kc) * 64 + (row | (kslot << 4))) * 8;

    uint32_t p0[8], p1[8], p2[8];
#pragma unroll
    for (int i = 0; i < 16; ++i) {
        unsigned short h0, h1, h2;
        split3(tile[g * 16 + i][vr], h0, h1, h2);
        if (i & 1) {
            p0[i >> 1] |= (uint32_t)h0 << 16;
            p1[i >> 1] |= (uint32_t)h1 << 16;
            p2[i >> 1] |= (uint32_t)h2 << 16;
        } else {
            p0[i >> 1] = h0; p1[i >> 1] = h1; p2[i >> 1] = h2;
        }
    }
    *(uint4*)&g_x0[off0]       = make_uint4(p0[0], p0[1], p0[2], p0[3]);
    *(uint4*)&g_x0[off0 + 128] = make_uint4(p0[4], p0[5], p0[6], p0[7]);
    *(uint4*)&g_x1[off0]       = make_uint4(p1[0], p1[1], p1[2], p1[3]);
    *(uint4*)&g_x1[off0 + 128] = make_uint4(p1[4], p1[5], p1[6], p1[7]);
    *(uint4*)&g_x2[off0]       = make_uint4(p2[0], p2[1], p2[2], p2[3]);
    *(uint4*)&g_x2[off0 + 128] = make_uint4(p2[4], p2[5], p2[6], p2[7]);
}

// ---------------------------------------------------------------------------
// GEMM v12: LDS-FREE, BARRIER-FREE MFMA. Fragments load straight from the
// fragment-ordered split arrays as coalesced 16B/lane global reads (A tiles
// shared by all 4 waves -> L1 broadcast; W 1.5 MB -> L2-hot; x from L3).
// Tile 32v x 128d x 1024s; grid (dblk2, vt16, b16) = 512 blocks = 2/CU.
// Wave w owns d [d0+32w, +32) = 2 n-tiles. Per chunk: 12 coalesced loads +
// 24 MFMA; no sync anywhere, compiler pipelines via vmcnt, 8 waves/CU TLP.
// Numerics verbatim r11 (passed): fp32 acc per 256-s quarter, fp64 flush
// ((q0+q1)+q2)+q3; MFMA order (a1b1)(a0b2)(a2b0)(a0b1)(a1b0)(a0b0).
// Epilogue verbatim r11: z=zac+bias fp64, nn2 shfl+LDS reduce -> g_nn2p.
// ---------------------------------------------------------------------------
__global__ __launch_bounds__(256) void gemm_kernel(const float* __restrict__ bias) {
    __shared__ double dred[4][32];

    const int t = threadIdx.x;
    const int dblk = blockIdx.x;    // 0..1
    const int vt   = blockIdx.y;    // 0..15
    const int b    = blockIdx.z;    // 0..15
    const int d0 = dblk * 128;
    const int v0 = vt * 32;
    const int w = t >> 6, l = t & 63;

    // Fragment base pointers (lane-resolved); kc stride = 512 elems (1 KB).
    const unsigned short* pa[3][2];
    const unsigned short* pb[3][2];
    {
        const unsigned short* xa[3] = {g_x0, g_x1, g_x2};
        const unsigned short* wa[3] = {g_w0, g_w1, g_w2};
#pragma unroll
        for (int sp = 0; sp < 3; ++sp) {
#pragma unroll
            for (int mb = 0; mb < 2; ++mb)
                pa[sp][mb] = xa[sp] +
                    ((((size_t)b * 32 + vt * 2 + mb) * 32) * 64 + l) * 8;
#pragma unroll
            for (int nb = 0; nb < 2; ++nb)
                pb[sp][nb] = wa[sp] +
                    (((size_t)(dblk * 8 + w * 2 + nb) * 32) * 64 + l) * 8;
        }
    }

    f32x4 acc[2][2];
    double zac[2][2][4];
#pragma unroll
    for (int mb = 0; mb < 2; ++mb)
#pragma unroll
        for (int nb = 0; nb < 2; ++nb) {
            acc[mb][nb] = (f32x4){0.f, 0.f, 0.f, 0.f};
#pragma unroll
            for (int r = 0; r < 4; ++r) zac[mb][nb][r] = 0.0;
        }

    for (int q = 0; q < 4; ++q) {           // 4 quarters of 8 chunks
        for (int c8 = 0; c8 < 8; ++c8) {
            bf16x8 a[3][2], bb[3][2];
#pragma unroll
            for (int sp = 0; sp < 3; ++sp) {
#pragma unroll
                for (int mb = 0; mb < 2; ++mb) {
                    a[sp][mb] = *(const bf16x8*)pa[sp][mb];
                    pa[sp][mb] += 512;
                }
#pragma unroll
                for (int nb = 0; nb < 2; ++nb) {
                    bb[sp][nb] = *(const bf16x8*)pb[sp][nb];
                    pb[sp][nb] += 512;
                }
            }
#pragma unroll
            for (int mb = 0; mb < 2; ++mb)
#pragma unroll
                for (int nb = 0; nb < 2; ++nb) {
                    f32x4 v = acc[mb][nb];
                    v = __builtin_amdgcn_mfma_f32_16x16x32_bf16(a[1][mb], bb[1][nb], v, 0, 0, 0);
                    v = __builtin_amdgcn_mfma_f32_16x16x32_bf16(a[0][mb], bb[2][nb], v, 0, 0, 0);
                    v = __builtin_amdgcn_mfma_f32_16x16x32_bf16(a[2][mb], bb[0][nb], v, 0, 0, 0);
                    v = __builtin_amdgcn_mfma_f32_16x16x32_bf16(a[0][mb], bb[1][nb], v, 0, 0, 0);
                    v = __builtin_amdgcn_mfma_f32_16x16x32_bf16(a[1][mb], bb[0][nb], v, 0, 0, 0);
                    v = __builtin_amdgcn_mfma_f32_16x16x32_bf16(a[0][mb], bb[0][nb], v, 0, 0, 0);
                    acc[mb][nb] = v;
                }
        }
        // Quarter boundary: flush fp32 partial into fp64 (r11-verbatim order).
#pragma unroll
        for (int mb = 0; mb < 2; ++mb)
#pragma unroll
            for (int nb = 0; nb < 2; ++nb) {
#pragma unroll
                for (int r = 0; r < 4; ++r)
                    zac[mb][nb][r] += (double)acc[mb][nb][r];
                acc[mb][nb] = (f32x4){0.f, 0.f, 0.f, 0.f};
            }
    }

    // Epilogue (r11 verbatim): z = zac + bias; nn2 partial over 128 d.
    double sv[2][4];
#pragma unroll
    for (int mb = 0; mb < 2; ++mb)
#pragma unroll
        for (int r = 0; r < 4; ++r) sv[mb][r] = 0.0;
#pragma unroll
    for (int mb = 0; mb < 2; ++mb)
#pragma unroll
        for (int nb = 0; nb < 2; ++nb) {
            const int d = d0 + w * 32 + nb * 16 + (l & 15);
            const double bd = (double)bias[d];
#pragma unroll
            for (int r = 0; r < 4; ++r) {
                double z = zac[mb][nb][r] + bd;
                sv[mb][r] += z * z;
            }
        }
#pragma unroll
    for (int mb = 0; mb < 2; ++mb)
#pragma unroll
        for (int r = 0; r < 4; ++r) {
            double s = sv[mb][r];
            s += __shfl_xor(s, 1);
            s += __shfl_xor(s, 2);
            s += __shfl_xor(s, 4);
            s += __shfl_xor(s, 8);
            sv[mb][r] = s;
        }
    if ((l & 15) == 0) {
#pragma unroll
        for (int mb = 0; mb < 2; ++mb)
#pragma unroll
            for (int r = 0; r < 4; ++r)
                dred[w][mb * 16 + (l >> 4) * 4 + r] = sv[mb][r];
    }
    __syncthreads();
    if (t < 32) {
        double s = dred[0][t] + dred[1][t] + dred[2][t] + dred[3][t];
        g_nn2p[dblk][b * NV + v0 + t] = s;
    }
}

// ---------------------------------------------------------------------------
// D-kernel (proven baseline): D_k partials over 128-s chunks, fp64.
// Grid: (vblk=8, b=16, sc=8) = 1024 blocks.
// ---------------------------------------------------------------------------
__global__ __launch_bounds__(256) void dkern(const float* __restrict__ x) {
    __shared__ double wcd[NK][128];
    __shared__ double dw[4][64][NK];
    const int t = threadIdx.x;
    const int vblk = blockIdx.x;
    const int b    = blockIdx.y;
    const int sc   = blockIdx.z;
    const int v0 = vblk * 64;
    const int ss = sc * 128;

#pragma unroll
    for (int j = 0; j < 4; ++j) {
        int idx = j * 256 + t;
        ((double*)wcd)[idx] = g_WC[(size_t)(idx >> 7) * SEQ + ss + (idx & 127)];
    }
    __syncthreads();

    const int vl = t & 63, w = t >> 6;
    const float* xp = x + (size_t)b * SEQ * NV + v0 + vl;
    double D[NK];
#pragma unroll
    for (int k = 0; k < NK; ++k) D[k] = 0.0;
    const int sw = w * 32;
    for (int i = 0; i < 32; ++i) {
        int sl = sw + i;
        double xv = (double)xp[(size_t)(ss + sl) * NV];
#pragma unroll
        for (int k = 0; k < NK; ++k) D[k] += xv * wcd[k][sl];
    }
#pragma unroll
    for (int k = 0; k < NK; ++k) dw[w][vl][k] = D[k];
    __syncthreads();

    const int v = t & 63, k2 = (t >> 6) * 2;
#pragma unroll
    for (int j = 0; j < 2; ++j) {
        int k = k2 + j;
        double s = dw[0][v][k] + dw[1][v][k] + dw[2][v][k] + dw[3][v][k];
        g_Dp[(((size_t)sc * BS + b) * NV + v0 + v) * NK + k] = s;
    }
}

// ---------------------------------------------------------------------------
// Finalize: n from the two deterministic dblk nn2 partials; rest unchanged.
// ---------------------------------------------------------------------------
__global__ __launch_bounds__(256) void finalize_kernel() {
    const int bv = blockIdx.x * 256 + threadIdx.x;
    double n = fmax(sqrt(g_nn2p[0][bv] + g_nn2p[1][bv]), 1e-12);

    double D[NK];
#pragma unroll
    for (int k = 0; k < NK; ++k) D[k] = g_Bk[k];
#pragma unroll
    for (int sc = 0; sc < 8; ++sc) {
#pragma unroll
        for (int k = 0; k < NK; ++k)
            D[k] += g_Dp[((size_t)sc * (BS * NV) + bv) * NK + k];
    }

    double p[NK], sum = 0.0;
#pragma unroll
    for (int k = 0; k < NK; ++k) {
        p[k] = exp((D[k] / n) / 0.05);
        sum += p[k];
    }
    unsigned int byte = 0;
#pragma unroll
    for (int k = 0; k < NK; ++k) {
        uint32_t i = (uint32_t)(k * (BS * NV) + bv);
        uint32_t y0, y1;
        threefry2x32_key7(0u, i, y0, y1);
        float u = bits_to_uniform(y0 ^ y1);
        if ((double)u < p[k] / sum) byte |= 1u << k;
    }
    g_bits[bv] = (unsigned char)byte;
}

// ---------------------------------------------------------------------------
// Write (unchanged): 268 MB broadcast, float4 stores — at HBM floor.
// ---------------------------------------------------------------------------
__global__ __launch_bounds__(256) void write_kernel(float* __restrict__ out) {
    const int t = threadIdx.x;
    const size_t r0 = (size_t)blockIdx.x * 8;
#pragma unroll
    for (int j = 0; j < 8; ++j) {
        size_t r = r0 + j;
        unsigned int bv = (unsigned int)(r & 8191u);
        unsigned int k  = (unsigned int)(r >> 13);
        float v = ((g_bits[bv] >> k) & 1u) ? 1.0f : 0.0f;
        float4 val = make_float4(v, v, v, v);
        ((float4*)(out + r * 1024))[t] = val;
    }
}

// ---------------------------------------------------------------------------
extern "C" void kernel_launch(void* const* d_in, const int* in_sizes, int n_in,
                              void* d_out, int out_size, void* d_ws, size_t ws_size,
                              hipStream_t stream) {
    const float* x    = (const float*)d_in[0];
    const float* W    = (const float*)d_in[1];
    const float* bias = (const float*)d_in[2];
    const float* ce   = (const float*)d_in[3];
    float* out = (float*)d_out;

    prep_kernel<<<dim3(96), dim3(256), 0, stream>>>(W, bias, ce);
    xsplit_kernel<<<dim3(128, 16), dim3(256), 0, stream>>>(x);
    gemm_kernel<<<dim3(2, 16, 16), dim3(256), 0, stream>>>(bias);
    dkern<<<dim3(8, 16, 8), dim3(256), 0, stream>>>(x);
    finalize_kernel<<<dim3(32), dim3(256), 0, stream>>>();
    write_kernel<<<dim3(8192), dim3(256), 0, stream>>>(out);
}